// Round 2
// baseline (308.395 us; speedup 1.0000x reference)
//
#include <hip/hip_runtime.h>

// Problem constants (from reference)
#define NF 10          // NUM_FEATURES
#define EMB 256        // EMBED_DIM
#define TOKENS (256*512)  // B*S = 131072 tokens
#define OUTW 512       // 2*EMBED_DIM per token
#define UNR 4          // grid-stride unroll: tokens-in-flight per thread

// Native vector type: __builtin_nontemporal_store requires a pointer to a
// scalar or clang vector type — HIP's float4 (HIP_vector_type) is rejected.
typedef float f32x4 __attribute__((ext_vector_type(4)));

// Block = 256 threads = 4 waves. Per unroll-slot a block covers 2 tokens:
//   threadIdx 0..127   -> token tok+0*stride..., threadIdx 128..255 -> token+1
//   q = t & 127: q<64  -> obs-embed float4 (e = 4q)        [waves 0, 2]
//                q>=64 -> pos-embed float4 (e = 4(q-64))   [waves 1, 3]
// Role is wave-uniform -> no divergence.
//
// R2 = R1 with the nontemporal-store type fixed. R1 theory:
//  - UNR=4 token-batches per iteration, ALL loads issued before any
//    compute/store -> 4x bytes-in-flight per wave per latency round
//    (R0 kernel was ~132 us at ~2 TB/s write BW = latency-bound at
//    16 waves/CU x 1 KB/round).
//  - x row loaded as 5 x float2 (row base = tok*40 B, 8B-aligned) instead
//    of 10 scalar dwords -> half the VMEM instructions per row.
//  - nontemporal stores: output is write-once, 268 MB >> L2; skip L2
//    write-allocate.
//  - __launch_bounds__(256,4): pin <=128 VGPR so unroll keeps 16 waves/CU.
__global__ __launch_bounds__(256, 4) void bert_embed_kernel(
    const float* __restrict__ x,    // [TOKENS, NF]
    const int*   __restrict__ doy,  // [TOKENS]
    const float* __restrict__ W,    // [EMB, NF]
    const float* __restrict__ bias, // [EMB]
    float*       __restrict__ out)  // [TOKENS, OUTW]
{
    const int t          = threadIdx.x;
    const int tok_in_blk = t >> 7;    // 0 or 1
    const int q          = t & 127;   // quad index within token
    const bool is_obs    = (q < 64);  // uniform per wave

    // ---- per-thread loop-invariant state ----
    float w[4][NF];
    float bv[4];
    float dv0 = 0.f, dv1 = 0.f;
    if (is_obs) {
        const int e0 = q * 4;
        #pragma unroll
        for (int r = 0; r < 4; ++r) {
            #pragma unroll
            for (int f = 0; f < NF; ++f) w[r][f] = W[(e0 + r) * NF + f];
            bv[r] = bias[e0 + r];
        }
    } else {
        const int e0 = (q - 64) * 4;  // even element base
        const float c = -9.210340371976184f / 256.0f;  // -ln(10000)/EMBED_DIM
        dv0 = __expf((float)e0 * c);
        dv1 = __expf((float)(e0 + 2) * c);
    }

    const int stride = gridDim.x * 2;   // tokens per grid step (4096 @ grid=2048)
    const int big    = stride * UNR;    // tokens per outer iter (16384)

    // grid=2048: TOKENS % big == 0 (131072 = 8 * 16384) -> no tail path;
    // every unroll slot is always in range.
    for (int tok = blockIdx.x * 2 + tok_in_blk; tok < TOKENS; tok += big) {
        if (is_obs) {
            // ---- issue ALL x-row loads first (wave-uniform -> L1 broadcast) ----
            float2 xv[UNR][5];
            #pragma unroll
            for (int u = 0; u < UNR; ++u) {
                const float2* xp = (const float2*)(x + (size_t)(tok + u * stride) * NF);
                #pragma unroll
                for (int j = 0; j < 5; ++j) xv[u][j] = xp[j];
            }
            // ---- compute + store per slot ----
            #pragma unroll
            for (int u = 0; u < UNR; ++u) {
                const float* xf = &xv[u][0].x;  // 10 floats, all indices static
                f32x4 o;
                #pragma unroll
                for (int r = 0; r < 4; ++r) {
                    float acc = bv[r];
                    #pragma unroll
                    for (int f = 0; f < NF; ++f) acc = fmaf(w[r][f], xf[f], acc);
                    o[r] = acc;
                }
                __builtin_nontemporal_store(o,
                    (f32x4*)(out + ((size_t)(tok + u * stride) << 9) + q * 4));
            }
        } else {
            // ---- issue ALL doy loads first (wave-uniform) ----
            int dd[UNR];
            #pragma unroll
            for (int u = 0; u < UNR; ++u) dd[u] = doy[tok + u * stride];
            #pragma unroll
            for (int u = 0; u < UNR; ++u) {
                f32x4 o;
                const int d = dd[u];  // wave-uniform -> uniform branch
                if (d == 0) {
                    o = (f32x4){0.f, 0.f, 0.f, 0.f};  // pe row 0 is zeros
                } else {
                    const float pos = (float)(d - 1);
                    const float a0 = pos * dv0;
                    const float a1 = pos * dv1;
                    // HW trig: v_fract + v_sin_f32 / v_cos_f32 (~3 instr,
                    // err ~2e-5 for |a| <= 365 rad; threshold is 0.0156)
                    o[0] = __sinf(a0); o[1] = __cosf(a0);
                    o[2] = __sinf(a1); o[3] = __cosf(a1);
                }
                __builtin_nontemporal_store(o,
                    (f32x4*)(out + ((size_t)(tok + u * stride) << 9) + EMB + (q - 64) * 4));
            }
        }
    }
}

extern "C" void kernel_launch(void* const* d_in, const int* in_sizes, int n_in,
                              void* d_out, int out_size, void* d_ws, size_t ws_size,
                              hipStream_t stream) {
    const float* x    = (const float*)d_in[0];  // input_sequence [B,S,NF] fp32
    const int*   doy  = (const int*)  d_in[1];  // doy_sequence   [B,S]    int32
    const float* W    = (const float*)d_in[2];  // W [EMB,NF] fp32
    const float* bias = (const float*)d_in[3];  // b [EMB]    fp32
    float*       out  = (float*)d_out;          // [B,S,2*EMB] fp32

    // 2048 blocks (8/CU) x 4 waves; each block covers 8 tokens/outer-iter ->
    // 8 outer iterations; stores are 16B/lane fully coalesced, 4 KB in
    // flight per wave per latency round.
    bert_embed_kernel<<<2048, 256, 0, stream>>>(x, doy, W, bias, out);
}